// Round 14
// baseline (1344.670 us; speedup 1.0000x reference)
//
#include <hip/hip_runtime.h>

// HMM forward (CgpHmmCell): B=512, T=4096, S=64, M=125.
// Round 14: wave-cooperative two-level probe extract.
//   Per row: 64 lanes read dwords 0..63 (256 B coalesced) -> ballot;
//   iff zero (P=61/125, WAVE-UNIFORM branch) read dwords 64..124 (244 B).
//   E[bytes/row] = 375 vs 500 (split at 64 is the minimizer of
//   f(k)=4k+(1-k/125)(500-4k)). 4 rows in flight/wave, 8192 waves -> the
//   serial probe-2 round-trip hides; HBM-bound at ~0.79 GB.
//   (R11's failure was per-THREAD rows: uncoalesced + exit at max over 64
//   lanes. Both fixed by the wave-cooperative form.)
// Scan bit-identical to R13 (absmax 0.0): permuted-K contraction
// (zero-shuffle C->B, pi absorbed into Af), constant 2^56 per-pack rescale
// (mass identity with constant offsets), de-chained MFMA pair, 128
// chunks/seq x 32 steps, burn 16, chunk-0 exact I*E0 override, 2 chains x
// 16 streams/wave, 2048 waves, one atomicAdd per wave.

#define BATCH 512
#define T 4096
#define S 64
#define M 125
#define CHUNKP 4   // packs per chunk (32 steps)
#define BURNP 2    // burn packs (16 steps)
#define NPACK 6
#define WPB 4
#define NQ 2       // chains per wave
#define RB 56.0f                       // log2 of per-pack constant rescale
#define SCALEF 7.205759403792794e16f   // 2^56

typedef __attribute__((ext_vector_type(8))) short bf16x8;
typedef __attribute__((ext_vector_type(4))) float f32x4;

union BFU { unsigned u[4]; bf16x8 v; };

__device__ __forceinline__ unsigned pk_trunc(float a, float b) {
    return (__float_as_uint(b) & 0xFFFF0000u) | (__float_as_uint(a) >> 16);
}
__device__ __forceinline__ unsigned pk_rne(float a, float b) {
    unsigned ua = __float_as_uint(a); ua += 0x7FFFu + ((ua >> 16) & 1u);
    unsigned ub = __float_as_uint(b); ub += 0x7FFFu + ((ub >> 16) & 1u);
    return (ub & 0xFFFF0000u) | (ua >> 16);
}

// ------- Phase 1: wave-cooperative two-level probe, 4 rows in flight -------
__global__ __launch_bounds__(256) void extract_obs(const float* __restrict__ x,
                                                   unsigned char* __restrict__ obs) {
    const int wv = threadIdx.x >> 6, lane = threadIdx.x & 63;
    const long long row0 = (long long)blockIdx.x * 1024 + wv * 256;
#pragma unroll 1
    for (int i = 0; i < 256; i += 4) {
        float v[4];
#pragma unroll
        for (int j = 0; j < 4; ++j)                 // 4 independent coalesced probes
            v[j] = x[(row0 + i + j) * (long long)M + lane];
#pragma unroll
        for (int j = 0; j < 4; ++j) {
            const long long r = row0 + i + j;
            unsigned long long m = __ballot(v[j] != 0.0f);
            int o;
            if (m) {                                // wave-uniform branch
                o = (int)__builtin_ctzll(m);
            } else {                                // P=0.488: second probe
                float v2 = (lane < M - 64) ? x[r * (long long)M + 64 + lane] : 0.0f;
                unsigned long long m2 = __ballot(v2 != 0.0f);
                o = 64 + (int)__builtin_ctzll(m2);
            }
            if (lane == 0) obs[r] = (unsigned char)o;
        }
    }
}

// ---------------- Phase 2: MFMA scan, 2 chains x 16 streams per wave --------
__global__ __launch_bounds__(256) void hmm_mfma(const unsigned char* __restrict__ obs,
                                                const float* __restrict__ Iv,
                                                const float* __restrict__ A,
                                                const float* __restrict__ Bm,
                                                float* __restrict__ out) {
    __shared__ __align__(16) float BmL[M * S];        // 32000 B
    __shared__ __align__(16) float ILds[S];

    const int tid = threadIdx.x, lane = tid & 63;
    const int s = lane & 15, g = lane >> 4;

    for (int i = tid; i < M * S; i += WPB * 64) BmL[i] = Bm[i];
    if (tid < S) ILds[tid] = Iv[tid];
    __syncthreads();

    // A^T fragments under pi: slot (kf,g,j2,e) holds A[p0+e][16mt+s],
    // p0 = 32kf + 16*(j2>>1) + 4g + 2*(j2&1).
    BFU Af[4][2];
#pragma unroll
    for (int mt = 0; mt < 4; ++mt)
#pragma unroll
        for (int kf = 0; kf < 2; ++kf)
#pragma unroll
            for (int j2 = 0; j2 < 4; ++j2) {
                int p0 = 32 * kf + 16 * (j2 >> 1) + 4 * g + 2 * (j2 & 1);
                Af[mt][kf].u[j2] = pk_rne(A[(size_t)p0 * S + mt * 16 + s],
                                          A[(size_t)(p0 + 1) * S + mt * 16 + s]);
            }

    const int W = blockIdx.x * WPB + (tid >> 6);  // 0..2047
    const int seq = W >> 2, quarter = W & 3;      // 4 waves per sequence
    const unsigned long long* orow = (const unsigned long long*)(obs + (size_t)seq * T);

    int idx0[NQ];
    unsigned long long u[NQ], un[NQ];
    BFU Bf[NQ][2];
    float S0v[NQ], swv[NQ];
#pragma unroll
    for (int q = 0; q < NQ; ++q) {
        int chunk = quarter * 32 + q * 16 + s;    // 0..127: this lane/chain's stream
        idx0[q] = chunk * CHUNKP - BURNP;
        u[q] = orow[idx0[q] < 0 ? 0 : idx0[q]];
        S0v[q] = 0.f; swv[q] = 1.f;
#pragma unroll
        for (int kf = 0; kf < 2; ++kf)
#pragma unroll
            for (int j = 0; j < 4; ++j) Bf[q][kf].u[j] = 0x3F803F80u;  // 1.0 seed
    }

    for (int p = 0; p < NPACK; ++p) {
#pragma unroll
        for (int q = 0; q < NQ; ++q) {
            int in_ = idx0[q] + p + 1;
            in_ = in_ < 0 ? 0 : (in_ > T / 8 - 1 ? T / 8 - 1 : in_);
            un[q] = orow[in_];                    // prefetch next pack
        }
        const bool ovp = (quarter == 0) && (p == BURNP);
        const bool massp = (p == BURNP - 1) || (p == NPACK - 1);
#pragma unroll
        for (int k = 0; k < 8; ++k) {
#pragma unroll
            for (int q = 0; q < NQ; ++q) {
                const int o = (int)((u[q] >> (8 * k)) & 255ull);
                const float* br = &BmL[o << 6];   // wave-uniform -> broadcast reads
                f32x4 E[4];
#pragma unroll
                for (int mt = 0; mt < 4; ++mt)
                    E[mt] = *(const f32x4*)&br[mt * 16 + g * 4];
                float w[4][4];
#pragma unroll
                for (int mt = 0; mt < 4; ++mt) {
                    f32x4 zr = {0.f, 0.f, 0.f, 0.f};
                    f32x4 z0 = __builtin_amdgcn_mfma_f32_16x16x32_bf16(Af[mt][0].v, Bf[q][0].v, zr, 0, 0, 0);
                    f32x4 z1 = __builtin_amdgcn_mfma_f32_16x16x32_bf16(Af[mt][1].v, Bf[q][1].v, zr, 0, 0, 0);
#pragma unroll
                    for (int r = 0; r < 4; ++r) w[mt][r] = (z0[r] + z1[r]) * E[mt][r];
                }
                if (ovp && k == 0 && q == 0) {    // exact t=0 init of chunk 0
                    const bool c0 = (s == 0);
#pragma unroll
                    for (int mt = 0; mt < 4; ++mt)
#pragma unroll
                        for (int r = 0; r < 4; ++r)
                            w[mt][r] = c0 ? ILds[mt * 16 + g * 4 + r] * E[mt][r] : w[mt][r];
                }
                if (k == 7 && massp) {            // mass only where needed
                    float swl = 0.f;
#pragma unroll
                    for (int mt = 0; mt < 4; ++mt)
#pragma unroll
                        for (int r = 0; r < 4; ++r) swl += w[mt][r];
                    swl += __shfl_xor(swl, 16);
                    swl += __shfl_xor(swl, 32);
                    swv[q] = swl;                 // pre-scale mass
                }
                // zero-shuffle C->B under pi; constant 2^56 rescale at k==7
#pragma unroll
                for (int kf = 0; kf < 2; ++kf)
#pragma unroll
                    for (int j2 = 0; j2 < 4; ++j2) {
                        int mt = 2 * kf + (j2 >> 1), pr = j2 & 1;
                        float v0 = w[mt][2 * pr], v1 = w[mt][2 * pr + 1];
                        if (k == 7) { v0 *= SCALEF; v1 *= SCALEF; }
                        Bf[q][kf].u[j2] = pk_trunc(v0, v1);
                    }
            }
        }
        if (p == BURNP - 1) {
            // stored = true*2^RB here; at final, stored = true*2^(5RB)
            // => C = log2(swf) - log2(swb) - 4RB; chunk0: C = log2(swf) - 3RB
#pragma unroll
            for (int q = 0; q < NQ; ++q) {
                const bool ch0 = (quarter == 0) && (q == 0) && (s == 0);
                S0v[q] = ch0 ? (3.0f * RB) : (__log2f(swv[q]) + 4.0f * RB);
            }
        }
#pragma unroll
        for (int q = 0; q < NQ; ++q) u[q] = un[q];
    }

    float tot = 0.f;
#pragma unroll
    for (int q = 0; q < NQ; ++q)
        tot += __log2f(swv[q]) - S0v[q];
    // sum over the 16 streams (s-dim); g-lanes hold duplicates
    tot += __shfl_xor(tot, 1);
    tot += __shfl_xor(tot, 2);
    tot += __shfl_xor(tot, 4);
    tot += __shfl_xor(tot, 8);
    if (lane == 0)
        atomicAdd(out + seq, tot * 0.6931471805599453f);
}

extern "C" void kernel_launch(void* const* d_in, const int* in_sizes, int n_in,
                              void* d_out, int out_size, void* d_ws, size_t ws_size,
                              hipStream_t stream) {
    const float* x  = (const float*)d_in[0];   // [B,T,M] one-hot
    const float* I  = (const float*)d_in[1];   // [1,S]
    const float* A  = (const float*)d_in[2];   // [S,S]
    const float* Bm = (const float*)d_in[3];   // [M,S]
    float* out = (float*)d_out;                // [B,1]
    unsigned char* obs = (unsigned char*)d_ws; // B*T = 2 MB of uint8

    hipMemsetAsync(out, 0, (size_t)out_size * sizeof(float), stream);
    // 2,097,152 rows / 1024 rows per block = 2048 blocks (8192 waves)
    extract_obs<<<2048, 256, 0, stream>>>(x, obs);
    hmm_mfma<<<512, WPB * 64, 0, stream>>>(obs, I, A, Bm, out);  // 2048 waves
}

// Round 15
// 1309.389 us; speedup vs baseline: 1.0269x; 1.0269x over previous
//
#include <hip/hip_runtime.h>

// HMM forward (CgpHmmCell): B=512, T=4096, S=64, M=125.
// Round 15: FULLY FUSED kernel — one-hot extraction overlapped with the
// MFMA scan (R13 ran them serially: extract 190us HBM-bound + scan 93us
// compute-bound). Each wave owns 16 consecutive chunks (CHUNKP=8 -> 64-row
// chunks; span = 1024 contiguous rows read exactly once). Extraction:
// wave-cooperative row read (lanes->dwords 0..63 and 61..124, 2 loads, no
// predication), 2 ballots -> o (SGPR); 8 o's packed into a u64 (scalar or)
// -> ONE predicated ds_write_b64 into a per-wave LDS table [stream][pack].
// Burn rows of chunk c == tail rows of chunk c-1: dual-deposit serves both
// (only 16 boundary rows/wave re-read ~1.6%). Software pipeline: pass Gp
// (rel [8p,8p+8), feeds pack p+2) runs inside scan pack p's k-loop (2 row
// groups per step, loads issued one step ahead); burn/K/L/PRE passes up
// front; packs 6..9 pure-scan tail. 2048 waves saturate HBM during waits.
// Scan core = R13 (absmax 0.0): permuted-K contraction (zero-shuffle C->B,
// pi absorbed into Af), constant 2^56/pack rescale, mass identity with
// constant offsets, de-chained MFMA, chunk-0 exact I*E0 override, NQ=1
// (16 streams/wave), one atomicAdd per wave. d_ws unused.

#define BATCH 512
#define T 4096
#define S 64
#define M 125
#define NPACK 10   // 2 burn + 8 accumulate (chunk = 64 steps)
#define BURNP 2
#define WPB 4
#define RB 56.0f
#define SCALEF 7.205759403792794e16f   // 2^56

typedef __attribute__((ext_vector_type(8))) short bf16x8;
typedef __attribute__((ext_vector_type(4))) float f32x4;

union BFU { unsigned u[4]; bf16x8 v; };

__device__ __forceinline__ unsigned pk_trunc(float a, float b) {
    return (__float_as_uint(b) & 0xFFFF0000u) | (__float_as_uint(a) >> 16);
}
__device__ __forceinline__ unsigned pk_rne(float a, float b) {
    unsigned ua = __float_as_uint(a); ua += 0x7FFFu + ((ua >> 16) & 1u);
    unsigned ub = __float_as_uint(b); ub += 0x7FFFu + ((ub >> 16) & 1u);
    return (ub & 0xFFFF0000u) | (ua >> 16);
}

__global__ __launch_bounds__(256) void hmm_fused(const float* __restrict__ x,
                                                 const float* __restrict__ Iv,
                                                 const float* __restrict__ A,
                                                 const float* __restrict__ Bm,
                                                 float* __restrict__ out) {
    __shared__ __align__(16) float BmL[M * S];                 // 32000 B
    __shared__ __align__(16) float ILds[S];
    __shared__ unsigned long long ulds[WPB * 16 * NPACK];      // 5120 B

    const int tid = threadIdx.x, wv = tid >> 6, lane = tid & 63;
    const int s = lane & 15, g = lane >> 4;

    for (int i = tid; i < M * S; i += WPB * 64) BmL[i] = Bm[i];
    if (tid < S) ILds[tid] = Iv[tid];
    __syncthreads();

    // A^T fragments under pi: slot (kf,g,j2,e) holds A[p0+e][16mt+s],
    // p0 = 32kf + 16*(j2>>1) + 4g + 2*(j2&1).
    BFU Af[4][2];
#pragma unroll
    for (int mt = 0; mt < 4; ++mt)
#pragma unroll
        for (int kf = 0; kf < 2; ++kf)
#pragma unroll
            for (int j2 = 0; j2 < 4; ++j2) {
                int p0 = 32 * kf + 16 * (j2 >> 1) + 4 * g + 2 * (j2 & 1);
                Af[mt][kf].u[j2] = pk_rne(A[(size_t)p0 * S + mt * 16 + s],
                                          A[(size_t)(p0 + 1) * S + mt * 16 + s]);
            }

    const int W = blockIdx.x * WPB + wv;   // 0..2047
    const int seq = W >> 2, wq = W & 3;    // 4 waves per sequence
    const float* xs = x + (size_t)seq * T * M;
    unsigned long long* myu = &ulds[wv * 16 * NPACK];
    const int base = wq * 1024;            // wave's first row (seq-relative)

    float bufA[16], bufB[16];              // 2 row-groups in flight

    auto issue16 = [&](int r0a, int r0b) { // load 8 rows at r0a, 8 at r0b
#pragma unroll
        for (int j = 0; j < 8; ++j) {
            unsigned ra = (unsigned)((r0a + j) * 125);
            unsigned rb = (unsigned)((r0b + j) * 125);
            bufA[j] = xs[ra + lane];       bufB[j] = xs[ra + 61 + lane];
            bufA[8 + j] = xs[rb + lane];   bufB[8 + j] = xs[rb + 61 + lane];
        }
    };
    auto ext8 = [&](int jb) -> unsigned long long {  // 8 rows -> packed o-bytes
        unsigned long long acc = 0;
#pragma unroll
        for (int j = 0; j < 8; ++j) {
            unsigned long long mA = __ballot(bufA[jb + j] != 0.0f);
            unsigned long long mB = __ballot(bufB[jb + j] != 0.0f);
            int o = mA ? (int)__builtin_ctzll(mA) : 61 + (int)__builtin_ctzll(mB);
            acc |= (unsigned long long)o << (8 * j);
        }
        return acc;
    };
    auto put = [&](int st, int pt, unsigned long long v) {
        if (lane == st) myu[st * NPACK + pt] = v;
    };

    // ---- Phase A: PRE (boundary burn) + K (rel 48..56) + L (rel 56..64) ----
    {
        int pa = base - 16, pb = base - 8;
        if (pa < 0) pa = 0;                // wq==0: garbage; chunk0 exact-init
        if (pb < 0) pb = 0;
        issue16(pa, pb);
        for (int gi = 0; gi <= 16; ++gi) {
            unsigned long long a0 = ext8(0), a1 = ext8(8);   // process current
            if (gi < 16) {                                   // issue next group
                int ni = gi + 1;
                if (ni <= 8) { int i = ni - 1; issue16(base + (2 * i) * 64 + 48, base + (2 * i + 1) * 64 + 48); }
                else         { int i = ni - 9; issue16(base + (2 * i) * 64 + 56, base + (2 * i + 1) * 64 + 56); }
            } else {
                issue16(base + 0, base + 64);                // G0/k0 (slot 0 step 0)
            }
            if (gi == 0) {                                   // PRE -> (0,p0),(0,p1)
                put(0, 0, a0); put(0, 1, a1);
            } else if (gi <= 8) {                            // K: (c,p8) & (c+1,p0)
                int i = gi - 1;
                put(2 * i, 8, a0);     put(2 * i + 1, 0, a0);
                put(2 * i + 1, 8, a1); if (2 * i + 2 <= 15) put(2 * i + 2, 0, a1);
            } else {                                         // L: (c,p9) & (c+1,p1)
                int i = gi - 9;
                put(2 * i, 9, a0);     put(2 * i + 1, 1, a0);
                put(2 * i + 1, 9, a1); if (2 * i + 2 <= 15) put(2 * i + 2, 1, a1);
            }
        }
    }

    // ---- Phase B: scan packs 0..9; packs 0..5 interleave passes G0..G5 ----
    BFU Bf[2];
#pragma unroll
    for (int kf = 0; kf < 2; ++kf)
#pragma unroll
        for (int j = 0; j < 4; ++j) Bf[kf].u[j] = 0x3F803F80u;  // 1.0 burn seed

    float S0v = 0.f, swv = 1.f;

    for (int p = 0; p < NPACK; ++p) {
        unsigned long long uv = myu[s * NPACK + p];   // this pack's o-bytes
        const bool exsl = (p < 6);
        for (int k = 0; k < 8; ++k) {
            if (exsl) {                               // extraction for pack p+2
                unsigned long long a0 = ext8(0), a1 = ext8(8);
                int np = (k == 7) ? p + 1 : p, nk = (k + 1) & 7;
                if (np < 6)                           // issue next step's rows
                    issue16(base + (2 * nk) * 64 + 8 * np,
                            base + (2 * nk + 1) * 64 + 8 * np);
                put(2 * k, p + 2, a0);
                put(2 * k + 1, p + 2, a1);
            }
            const int o = (int)(uv & 255ull);
            uv >>= 8;
            const float* br = &BmL[o << 6];           // wave-uniform broadcast
            f32x4 E[4];
#pragma unroll
            for (int mt = 0; mt < 4; ++mt)
                E[mt] = *(const f32x4*)&br[mt * 16 + g * 4];
            float w[4][4];
#pragma unroll
            for (int mt = 0; mt < 4; ++mt) {
                f32x4 zr = {0.f, 0.f, 0.f, 0.f};
                f32x4 z0 = __builtin_amdgcn_mfma_f32_16x16x32_bf16(Af[mt][0].v, Bf[0].v, zr, 0, 0, 0);
                f32x4 z1 = __builtin_amdgcn_mfma_f32_16x16x32_bf16(Af[mt][1].v, Bf[1].v, zr, 0, 0, 0);
#pragma unroll
                for (int r = 0; r < 4; ++r) w[mt][r] = (z0[r] + z1[r]) * E[mt][r];
            }
            if (p == BURNP && k == 0 && wq == 0) {    // exact t=0 init of chunk 0
                const bool c0 = (s == 0);
#pragma unroll
                for (int mt = 0; mt < 4; ++mt)
#pragma unroll
                    for (int r = 0; r < 4; ++r)
                        w[mt][r] = c0 ? ILds[mt * 16 + g * 4 + r] * E[mt][r] : w[mt][r];
            }
            if (k == 7 && (p == BURNP - 1 || p == NPACK - 1)) {  // mass (pre-scale)
                float swl = 0.f;
#pragma unroll
                for (int mt = 0; mt < 4; ++mt)
#pragma unroll
                    for (int r = 0; r < 4; ++r) swl += w[mt][r];
                swl += __shfl_xor(swl, 16);
                swl += __shfl_xor(swl, 32);
                swv = swl;
            }
            // zero-shuffle C->B under pi; constant 2^56 rescale at k==7
#pragma unroll
            for (int kf = 0; kf < 2; ++kf)
#pragma unroll
                for (int j2 = 0; j2 < 4; ++j2) {
                    int mt = 2 * kf + (j2 >> 1), pr = j2 & 1;
                    float v0 = w[mt][2 * pr], v1 = w[mt][2 * pr + 1];
                    if (k == 7) { v0 *= SCALEF; v1 *= SCALEF; }
                    Bf[kf].u[j2] = pk_trunc(v0, v1);
                }
        }
        if (p == BURNP - 1) {
            // exponents: burn mass carries 1*RB, final carries (NPACK-1)*RB
            // => S0 = log2(swb) + (NPACK-BURNP)*RB; chunk0: (NPACK-1-BURNP)*RB
            const bool ch0 = (wq == 0) && (s == 0);
            S0v = ch0 ? ((float)(NPACK - 1 - BURNP) * RB)
                      : (__log2f(swv) + (float)(NPACK - BURNP) * RB);
        }
    }

    float tot = __log2f(swv) - S0v;
    // sum over the 16 streams (s-dim); g-lanes hold duplicates
    tot += __shfl_xor(tot, 1);
    tot += __shfl_xor(tot, 2);
    tot += __shfl_xor(tot, 4);
    tot += __shfl_xor(tot, 8);
    if (lane == 0)
        atomicAdd(out + seq, tot * 0.6931471805599453f);
}

extern "C" void kernel_launch(void* const* d_in, const int* in_sizes, int n_in,
                              void* d_out, int out_size, void* d_ws, size_t ws_size,
                              hipStream_t stream) {
    const float* x  = (const float*)d_in[0];   // [B,T,M] one-hot
    const float* I  = (const float*)d_in[1];   // [1,S]
    const float* A  = (const float*)d_in[2];   // [S,S]
    const float* Bm = (const float*)d_in[3];   // [M,S]
    float* out = (float*)d_out;                // [B,1]
    (void)d_ws; (void)ws_size;                 // workspace unused (fully fused)

    hipMemsetAsync(out, 0, (size_t)out_size * sizeof(float), stream);
    hmm_fused<<<(BATCH * 4) / WPB, WPB * 64, 0, stream>>>(x, I, A, Bm, out);  // 2048 waves
}

// Round 16
// 1305.306 us; speedup vs baseline: 1.0302x; 1.0031x over previous
//
#include <hip/hip_runtime.h>

// HMM forward (CgpHmmCell): B=512, T=4096, S=64, M=125.
// Round 16: R15's fused structure (schedule/mapping identical, absmax 0.0)
// with two mechanical fixes:
//  (1) MFMA-FIRST step order: the extraction block (which carries the
//      s_waitcnt vmcnt for last step's loads) now sits between MFMA issue
//      and MFMA consumption, so the load wait hides under the matrix pipe.
//      R15 had extraction first -> every step serialized load-wait+compute.
//  (2) one dwordx4 loads TWO rows (lanes 0..31 row r: dwords 4*rel /
//      121..124 for rel=31 (overlap, never OOB); lanes 32..63 row r+1):
//      8 VMEM instr per 16-row group (was 32), 1 KB/instr. o per row =
//      ballot(any nz) -> uniform ctz lane -> readlane(first-nz dword idx).
// Everything else unchanged: per-wave 16 consecutive 64-row chunks,
// dual-deposit boundary rows, Phase A = PRE+K+L (packs 0,1,8,9), in-loop
// passes p=0..5 feed packs 2..7 (prefetch distance 2), permuted-K MFMA
// contraction, constant 2^56/pack rescale, mass identity, chunk-0 exact
// I*E0 override, one atomicAdd per wave. d_ws unused.

#define BATCH 512
#define T 4096
#define S 64
#define M 125
#define NPACK 10   // 2 burn + 8 accumulate (chunk = 64 steps)
#define BURNP 2
#define WPB 4
#define RB 56.0f
#define SCALEF 7.205759403792794e16f   // 2^56

typedef __attribute__((ext_vector_type(8))) short bf16x8;
typedef __attribute__((ext_vector_type(4))) float f32x4;
typedef float f32x4u __attribute__((ext_vector_type(4), aligned(4)));  // 4-B-aligned vec4

union BFU { unsigned u[4]; bf16x8 v; };

__device__ __forceinline__ unsigned pk_trunc(float a, float b) {
    return (__float_as_uint(b) & 0xFFFF0000u) | (__float_as_uint(a) >> 16);
}
__device__ __forceinline__ unsigned pk_rne(float a, float b) {
    unsigned ua = __float_as_uint(a); ua += 0x7FFFu + ((ua >> 16) & 1u);
    unsigned ub = __float_as_uint(b); ub += 0x7FFFu + ((ub >> 16) & 1u);
    return (ub & 0xFFFF0000u) | (ua >> 16);
}

__global__ __launch_bounds__(256) void hmm_fused(const float* __restrict__ x,
                                                 const float* __restrict__ Iv,
                                                 const float* __restrict__ A,
                                                 const float* __restrict__ Bm,
                                                 float* __restrict__ out) {
    __shared__ __align__(16) float BmL[M * S];                 // 32000 B
    __shared__ __align__(16) float ILds[S];
    __shared__ unsigned long long ulds[WPB * 16 * NPACK];      // 5120 B

    const int tid = threadIdx.x, wv = tid >> 6, lane = tid & 63;
    const int s = lane & 15, g = lane >> 4;

    for (int i = tid; i < M * S; i += WPB * 64) BmL[i] = Bm[i];
    if (tid < S) ILds[tid] = Iv[tid];
    __syncthreads();

    // A^T fragments under pi: slot (kf,g,j2,e) holds A[p0+e][16mt+s],
    // p0 = 32kf + 16*(j2>>1) + 4g + 2*(j2&1).
    BFU Af[4][2];
#pragma unroll
    for (int mt = 0; mt < 4; ++mt)
#pragma unroll
        for (int kf = 0; kf < 2; ++kf)
#pragma unroll
            for (int j2 = 0; j2 < 4; ++j2) {
                int p0 = 32 * kf + 16 * (j2 >> 1) + 4 * g + 2 * (j2 & 1);
                Af[mt][kf].u[j2] = pk_rne(A[(size_t)p0 * S + mt * 16 + s],
                                          A[(size_t)(p0 + 1) * S + mt * 16 + s]);
            }

    const int W = blockIdx.x * WPB + wv;   // 0..2047
    const int seq = W >> 2, wq = W & 3;    // 4 waves per sequence
    const float* xs = x + (size_t)seq * T * M;
    unsigned long long* myu = &ulds[wv * 16 * NPACK];
    const int base = wq * 1024;            // wave's first row (seq-relative)

    const int rel = lane & 31, hf = lane >> 5;
    const unsigned coff = (rel < 31) ? 4u * (unsigned)rel : 121u;  // dword in row

    f32x4u buf4[8];                        // 16 rows in flight (2 rows/load)

    auto issue16 = [&](int r0a, int r0b) { // 8 rows at r0a, 8 at r0b
#pragma unroll
        for (int j = 0; j < 4; ++j) {
            unsigned ra = (unsigned)((r0a + 2 * j + hf) * 125) + coff;
            unsigned rb = (unsigned)((r0b + 2 * j + hf) * 125) + coff;
            buf4[j]     = *(const f32x4u*)&xs[ra];
            buf4[4 + j] = *(const f32x4u*)&xs[rb];
        }
    };
    auto ext8 = [&](int b) -> unsigned long long {  // block b in {0,1} -> 8 o-bytes
        unsigned long long acc = 0;
#pragma unroll
        for (int j = 0; j < 4; ++j) {
            f32x4u v = buf4[b * 4 + j];
            bool nz = (v.x != 0.f) || (v.y != 0.f) || (v.z != 0.f) || (v.w != 0.f);
            unsigned li = (v.x != 0.f) ? 0u : ((v.y != 0.f) ? 1u : ((v.z != 0.f) ? 2u : 3u));
            unsigned cand = coff + li;                 // dword index of first nz here
            unsigned long long m = __ballot(nz);       // one-hot => both halves nonzero
            unsigned l0 = (unsigned)__builtin_ctzll(m & 0xffffffffull);
            unsigned l1 = (unsigned)__builtin_ctzll(m >> 32);
            unsigned o0 = __builtin_amdgcn_readlane(cand, l0);        // row 2j
            unsigned o1 = __builtin_amdgcn_readlane(cand, 32 + l1);   // row 2j+1
            acc |= ((unsigned long long)o0 << (16 * j)) |
                   ((unsigned long long)o1 << (16 * j + 8));
        }
        return acc;
    };
    auto put = [&](int st, int pt, unsigned long long v) {
        if (lane == st) myu[st * NPACK + pt] = v;
    };

    // ---- Phase A: PRE (boundary burn) + K (rel 48..56) + L (rel 56..64) ----
    {
        int pa = base - 16, pb = base - 8;
        if (pa < 0) pa = 0;                // wq==0: garbage; chunk0 exact-init
        if (pb < 0) pb = 0;
        issue16(pa, pb);
        for (int gi = 0; gi <= 16; ++gi) {
            unsigned long long a0 = ext8(0), a1 = ext8(1);   // process current
            if (gi < 16) {                                   // issue next group
                int ni = gi + 1;
                if (ni <= 8) { int i = ni - 1; issue16(base + (2 * i) * 64 + 48, base + (2 * i + 1) * 64 + 48); }
                else         { int i = ni - 9; issue16(base + (2 * i) * 64 + 56, base + (2 * i + 1) * 64 + 56); }
            } else {
                issue16(base + 0, base + 64);                // G0/k0 (slot 0 step 0)
            }
            if (gi == 0) {                                   // PRE -> (0,p0),(0,p1)
                put(0, 0, a0); put(0, 1, a1);
            } else if (gi <= 8) {                            // K: (c,p8) & (c+1,p0)
                int i = gi - 1;
                put(2 * i, 8, a0);     put(2 * i + 1, 0, a0);
                put(2 * i + 1, 8, a1); if (2 * i + 2 <= 15) put(2 * i + 2, 0, a1);
            } else {                                         // L: (c,p9) & (c+1,p1)
                int i = gi - 9;
                put(2 * i, 9, a0);     put(2 * i + 1, 1, a0);
                put(2 * i + 1, 9, a1); if (2 * i + 2 <= 15) put(2 * i + 2, 1, a1);
            }
        }
    }

    // ---- Phase B: scan packs 0..9; packs 0..5 interleave passes G0..G5 ----
    BFU Bf[2];
#pragma unroll
    for (int kf = 0; kf < 2; ++kf)
#pragma unroll
        for (int j = 0; j < 4; ++j) Bf[kf].u[j] = 0x3F803F80u;  // 1.0 burn seed

    float S0v = 0.f, swv = 1.f;

    for (int p = 0; p < NPACK; ++p) {
        unsigned long long uv = myu[s * NPACK + p];   // this pack's o-bytes
        const bool exsl = (p < 6);
        for (int k = 0; k < 8; ++k) {
            // --- MFMA section FIRST (issue, don't consume yet) ---
            const int o = (int)(uv & 255ull);
            uv >>= 8;
            const float* br = &BmL[o << 6];           // wave-uniform broadcast
            f32x4 E[4], z0[4], z1[4];
#pragma unroll
            for (int mt = 0; mt < 4; ++mt) {
                E[mt] = *(const f32x4*)&br[mt * 16 + g * 4];
                f32x4 zr = {0.f, 0.f, 0.f, 0.f};
                z0[mt] = __builtin_amdgcn_mfma_f32_16x16x32_bf16(Af[mt][0].v, Bf[0].v, zr, 0, 0, 0);
                z1[mt] = __builtin_amdgcn_mfma_f32_16x16x32_bf16(Af[mt][1].v, Bf[1].v, zr, 0, 0, 0);
            }
            // --- extraction: its vmcnt wait overlaps the MFMAs above ---
            if (exsl) {                               // extraction for pack p+2
                unsigned long long a0 = ext8(0), a1 = ext8(1);
                int np = (k == 7) ? p + 1 : p, nk = (k + 1) & 7;
                if (np < 6)                           // issue next step's rows
                    issue16(base + (2 * nk) * 64 + 8 * np,
                            base + (2 * nk + 1) * 64 + 8 * np);
                put(2 * k, p + 2, a0);
                put(2 * k + 1, p + 2, a1);
            }
            // --- consume MFMA results ---
            float w[4][4];
#pragma unroll
            for (int mt = 0; mt < 4; ++mt)
#pragma unroll
                for (int r = 0; r < 4; ++r) w[mt][r] = (z0[mt][r] + z1[mt][r]) * E[mt][r];
            if (p == BURNP && k == 0 && wq == 0) {    // exact t=0 init of chunk 0
                const bool c0 = (s == 0);
#pragma unroll
                for (int mt = 0; mt < 4; ++mt)
#pragma unroll
                    for (int r = 0; r < 4; ++r)
                        w[mt][r] = c0 ? ILds[mt * 16 + g * 4 + r] * E[mt][r] : w[mt][r];
            }
            if (k == 7 && (p == BURNP - 1 || p == NPACK - 1)) {  // mass (pre-scale)
                float swl = 0.f;
#pragma unroll
                for (int mt = 0; mt < 4; ++mt)
#pragma unroll
                    for (int r = 0; r < 4; ++r) swl += w[mt][r];
                swl += __shfl_xor(swl, 16);
                swl += __shfl_xor(swl, 32);
                swv = swl;
            }
            // zero-shuffle C->B under pi; constant 2^56 rescale at k==7
#pragma unroll
            for (int kf = 0; kf < 2; ++kf)
#pragma unroll
                for (int j2 = 0; j2 < 4; ++j2) {
                    int mt = 2 * kf + (j2 >> 1), pr = j2 & 1;
                    float v0 = w[mt][2 * pr], v1 = w[mt][2 * pr + 1];
                    if (k == 7) { v0 *= SCALEF; v1 *= SCALEF; }
                    Bf[kf].u[j2] = pk_trunc(v0, v1);
                }
        }
        if (p == BURNP - 1) {
            // exponents: burn mass carries 1*RB, final carries (NPACK-1)*RB
            const bool ch0 = (wq == 0) && (s == 0);
            S0v = ch0 ? ((float)(NPACK - 1 - BURNP) * RB)
                      : (__log2f(swv) + (float)(NPACK - BURNP) * RB);
        }
    }

    float tot = __log2f(swv) - S0v;
    // sum over the 16 streams (s-dim); g-lanes hold duplicates
    tot += __shfl_xor(tot, 1);
    tot += __shfl_xor(tot, 2);
    tot += __shfl_xor(tot, 4);
    tot += __shfl_xor(tot, 8);
    if (lane == 0)
        atomicAdd(out + seq, tot * 0.6931471805599453f);
}

extern "C" void kernel_launch(void* const* d_in, const int* in_sizes, int n_in,
                              void* d_out, int out_size, void* d_ws, size_t ws_size,
                              hipStream_t stream) {
    const float* x  = (const float*)d_in[0];   // [B,T,M] one-hot
    const float* I  = (const float*)d_in[1];   // [1,S]
    const float* A  = (const float*)d_in[2];   // [S,S]
    const float* Bm = (const float*)d_in[3];   // [M,S]
    float* out = (float*)d_out;                // [B,1]
    (void)d_ws; (void)ws_size;                 // workspace unused (fully fused)

    hipMemsetAsync(out, 0, (size_t)out_size * sizeof(float), stream);
    hmm_fused<<<(BATCH * 4) / WPB, WPB * 64, 0, stream>>>(x, I, A, Bm, out);  // 2048 waves
}

// Round 17
// 1300.665 us; speedup vs baseline: 1.0338x; 1.0036x over previous
//
#include <hip/hip_runtime.h>

// HMM forward (CgpHmmCell): B=512, T=4096, S=64, M=125.
// Round 17: R16 + PREFETCH DISTANCE 2. R16's fused kernel showed zero
// extract/scan overlap (274us ~= 93+190 serial): loads issued at step n-1
// (~350 cyc) can't cover ~1100-1500 cyc congested HBM latency -> every step
// stalls on vmcnt. Fix: ping-pong row buffers bufP/bufQ; step n consumes the
// buffer filled at n-2 and refills it for n+2. Buffer parity = k&1
// (n=8p+k, 8p even) -> compile-time selection in the unrolled k-loop.
// Issue target moves from k+1 to k+2 (wraps to pack p+1 for k>=6; suppressed
// when p+1>=6). Phase A ends by filling bufP(step0: blocks base+0,base+64)
// and bufQ(step1: blocks base+128,base+192).
// Everything else identical to R16 (absmax 0.0): per-wave 16 consecutive
// 64-row chunks, dual-deposit boundary rows, Phase A = PRE+K+L (packs
// 0,1,8,9), in-loop passes feed packs 2..7, permuted-K MFMA contraction,
// constant 2^56/pack rescale, mass identity, chunk-0 exact I*E0 override,
// one atomicAdd per wave. d_ws unused.

#define BATCH 512
#define T 4096
#define S 64
#define M 125
#define NPACK 10   // 2 burn + 8 accumulate (chunk = 64 steps)
#define BURNP 2
#define WPB 4
#define RB 56.0f
#define SCALEF 7.205759403792794e16f   // 2^56

typedef __attribute__((ext_vector_type(8))) short bf16x8;
typedef __attribute__((ext_vector_type(4))) float f32x4;
typedef float f32x4u __attribute__((ext_vector_type(4), aligned(4)));  // 4-B-aligned vec4

union BFU { unsigned u[4]; bf16x8 v; };

__device__ __forceinline__ unsigned pk_trunc(float a, float b) {
    return (__float_as_uint(b) & 0xFFFF0000u) | (__float_as_uint(a) >> 16);
}
__device__ __forceinline__ unsigned pk_rne(float a, float b) {
    unsigned ua = __float_as_uint(a); ua += 0x7FFFu + ((ua >> 16) & 1u);
    unsigned ub = __float_as_uint(b); ub += 0x7FFFu + ((ub >> 16) & 1u);
    return (ub & 0xFFFF0000u) | (ua >> 16);
}

__global__ __launch_bounds__(256) void hmm_fused(const float* __restrict__ x,
                                                 const float* __restrict__ Iv,
                                                 const float* __restrict__ A,
                                                 const float* __restrict__ Bm,
                                                 float* __restrict__ out) {
    __shared__ __align__(16) float BmL[M * S];                 // 32000 B
    __shared__ __align__(16) float ILds[S];
    __shared__ unsigned long long ulds[WPB * 16 * NPACK];      // 5120 B

    const int tid = threadIdx.x, wv = tid >> 6, lane = tid & 63;
    const int s = lane & 15, g = lane >> 4;

    for (int i = tid; i < M * S; i += WPB * 64) BmL[i] = Bm[i];
    if (tid < S) ILds[tid] = Iv[tid];
    __syncthreads();

    // A^T fragments under pi: slot (kf,g,j2,e) holds A[p0+e][16mt+s],
    // p0 = 32kf + 16*(j2>>1) + 4g + 2*(j2&1).
    BFU Af[4][2];
#pragma unroll
    for (int mt = 0; mt < 4; ++mt)
#pragma unroll
        for (int kf = 0; kf < 2; ++kf)
#pragma unroll
            for (int j2 = 0; j2 < 4; ++j2) {
                int p0 = 32 * kf + 16 * (j2 >> 1) + 4 * g + 2 * (j2 & 1);
                Af[mt][kf].u[j2] = pk_rne(A[(size_t)p0 * S + mt * 16 + s],
                                          A[(size_t)(p0 + 1) * S + mt * 16 + s]);
            }

    const int W = blockIdx.x * WPB + wv;   // 0..2047
    const int seq = W >> 2, wq = W & 3;    // 4 waves per sequence
    const float* xs = x + (size_t)seq * T * M;
    unsigned long long* myu = &ulds[wv * 16 * NPACK];
    const int base = wq * 1024;            // wave's first row (seq-relative)

    const int rel = lane & 31, hf = lane >> 5;
    const unsigned coff = (rel < 31) ? 4u * (unsigned)rel : 121u;  // dword in row

    f32x4u bufP[8], bufQ[8];               // ping-pong: 2 x 16 rows in flight

    auto issue16 = [&](f32x4u (&bf)[8], int r0a, int r0b) {
#pragma unroll
        for (int j = 0; j < 4; ++j) {
            unsigned ra = (unsigned)((r0a + 2 * j + hf) * 125) + coff;
            unsigned rb = (unsigned)((r0b + 2 * j + hf) * 125) + coff;
            bf[j]     = *(const f32x4u*)&xs[ra];
            bf[4 + j] = *(const f32x4u*)&xs[rb];
        }
    };
    auto ext8 = [&](const f32x4u (&bf)[8], int b) -> unsigned long long {
        unsigned long long acc = 0;
#pragma unroll
        for (int j = 0; j < 4; ++j) {
            f32x4u v = bf[b * 4 + j];
            bool nz = (v.x != 0.f) || (v.y != 0.f) || (v.z != 0.f) || (v.w != 0.f);
            unsigned li = (v.x != 0.f) ? 0u : ((v.y != 0.f) ? 1u : ((v.z != 0.f) ? 2u : 3u));
            unsigned cand = coff + li;                 // dword index of first nz here
            unsigned long long m = __ballot(nz);       // one-hot => both halves nonzero
            unsigned l0 = (unsigned)__builtin_ctzll(m & 0xffffffffull);
            unsigned l1 = (unsigned)__builtin_ctzll(m >> 32);
            unsigned o0 = __builtin_amdgcn_readlane(cand, l0);        // row 2j
            unsigned o1 = __builtin_amdgcn_readlane(cand, 32 + l1);   // row 2j+1
            acc |= ((unsigned long long)o0 << (16 * j)) |
                   ((unsigned long long)o1 << (16 * j + 8));
        }
        return acc;
    };
    auto put = [&](int st, int pt, unsigned long long v) {
        if (lane == st) myu[st * NPACK + pt] = v;
    };

    // ---- Phase A: PRE (boundary burn) + K (rel 48..56) + L (rel 56..64) ----
    {
        int pa = base - 16, pb = base - 8;
        if (pa < 0) pa = 0;                // wq==0: garbage; chunk0 exact-init
        if (pb < 0) pb = 0;
        issue16(bufP, pa, pb);
        for (int gi = 0; gi <= 16; ++gi) {
            unsigned long long a0 = ext8(bufP, 0), a1 = ext8(bufP, 1);
            if (gi < 16) {                                   // issue next group
                int ni = gi + 1;
                if (ni <= 8) { int i = ni - 1; issue16(bufP, base + (2 * i) * 64 + 48, base + (2 * i + 1) * 64 + 48); }
                else         { int i = ni - 9; issue16(bufP, base + (2 * i) * 64 + 56, base + (2 * i + 1) * 64 + 56); }
            } else {
                issue16(bufP, base + 0, base + 64);          // step 0 (p0,k0)
            }
            if (gi == 0) {                                   // PRE -> (0,p0),(0,p1)
                put(0, 0, a0); put(0, 1, a1);
            } else if (gi <= 8) {                            // K: (c,p8) & (c+1,p0)
                int i = gi - 1;
                put(2 * i, 8, a0);     put(2 * i + 1, 0, a0);
                put(2 * i + 1, 8, a1); if (2 * i + 2 <= 15) put(2 * i + 2, 0, a1);
            } else {                                         // L: (c,p9) & (c+1,p1)
                int i = gi - 9;
                put(2 * i, 9, a0);     put(2 * i + 1, 1, a0);
                put(2 * i + 1, 9, a1); if (2 * i + 2 <= 15) put(2 * i + 2, 1, a1);
            }
        }
        issue16(bufQ, base + 128, base + 192);               // step 1 (p0,k1)
    }

    // ---- Phase B: scan packs 0..9; packs 0..5 interleave extraction ----
    BFU Bf[2];
#pragma unroll
    for (int kf = 0; kf < 2; ++kf)
#pragma unroll
        for (int j = 0; j < 4; ++j) Bf[kf].u[j] = 0x3F803F80u;  // 1.0 burn seed

    float S0v = 0.f, swv = 1.f;

    for (int p = 0; p < NPACK; ++p) {
        unsigned long long uv = myu[s * NPACK + p];   // this pack's o-bytes
        const bool exsl = (p < 6);
#pragma unroll
        for (int k = 0; k < 8; ++k) {
            // --- MFMA section first (issue, don't consume yet) ---
            const int o = (int)(uv & 255ull);
            uv >>= 8;
            const float* br = &BmL[o << 6];           // wave-uniform broadcast
            f32x4 E[4], z0[4], z1[4];
#pragma unroll
            for (int mt = 0; mt < 4; ++mt) {
                E[mt] = *(const f32x4*)&br[mt * 16 + g * 4];
                f32x4 zr = {0.f, 0.f, 0.f, 0.f};
                z0[mt] = __builtin_amdgcn_mfma_f32_16x16x32_bf16(Af[mt][0].v, Bf[0].v, zr, 0, 0, 0);
                z1[mt] = __builtin_amdgcn_mfma_f32_16x16x32_bf16(Af[mt][1].v, Bf[1].v, zr, 0, 0, 0);
            }
            // --- extraction (vmcnt wait overlaps MFMAs); distance-2 refill ---
            if (exsl) {
                unsigned long long a0, a1;
                // k is compile-time (unrolled): buffer parity = k&1
                if ((k & 1) == 0) { a0 = ext8(bufP, 0); a1 = ext8(bufP, 1); }
                else              { a0 = ext8(bufQ, 0); a1 = ext8(bufQ, 1); }
                int k2 = k + 2, p2 = p;
                bool ok = true;
                if (k2 >= 8) { k2 -= 8; p2 = p + 1; ok = (p2 < 6); }
                if (ok) {
                    int r0a = base + (2 * k2) * 64 + 8 * p2;
                    if ((k & 1) == 0) issue16(bufP, r0a, r0a + 64);
                    else              issue16(bufQ, r0a, r0a + 64);
                }
                put(2 * k, p + 2, a0);
                put(2 * k + 1, p + 2, a1);
            }
            // --- consume MFMA results ---
            float w[4][4];
#pragma unroll
            for (int mt = 0; mt < 4; ++mt)
#pragma unroll
                for (int r = 0; r < 4; ++r) w[mt][r] = (z0[mt][r] + z1[mt][r]) * E[mt][r];
            if (p == BURNP && k == 0 && wq == 0) {    // exact t=0 init of chunk 0
                const bool c0 = (s == 0);
#pragma unroll
                for (int mt = 0; mt < 4; ++mt)
#pragma unroll
                    for (int r = 0; r < 4; ++r)
                        w[mt][r] = c0 ? ILds[mt * 16 + g * 4 + r] * E[mt][r] : w[mt][r];
            }
            if (k == 7 && (p == BURNP - 1 || p == NPACK - 1)) {  // mass (pre-scale)
                float swl = 0.f;
#pragma unroll
                for (int mt = 0; mt < 4; ++mt)
#pragma unroll
                    for (int r = 0; r < 4; ++r) swl += w[mt][r];
                swl += __shfl_xor(swl, 16);
                swl += __shfl_xor(swl, 32);
                swv = swl;
            }
            // zero-shuffle C->B under pi; constant 2^56 rescale at k==7
#pragma unroll
            for (int kf = 0; kf < 2; ++kf)
#pragma unroll
                for (int j2 = 0; j2 < 4; ++j2) {
                    int mt = 2 * kf + (j2 >> 1), pr = j2 & 1;
                    float v0 = w[mt][2 * pr], v1 = w[mt][2 * pr + 1];
                    if (k == 7) { v0 *= SCALEF; v1 *= SCALEF; }
                    Bf[kf].u[j2] = pk_trunc(v0, v1);
                }
        }
        if (p == BURNP - 1) {
            // exponents: burn mass carries 1*RB, final carries (NPACK-1)*RB
            const bool ch0 = (wq == 0) && (s == 0);
            S0v = ch0 ? ((float)(NPACK - 1 - BURNP) * RB)
                      : (__log2f(swv) + (float)(NPACK - BURNP) * RB);
        }
    }

    float tot = __log2f(swv) - S0v;
    // sum over the 16 streams (s-dim); g-lanes hold duplicates
    tot += __shfl_xor(tot, 1);
    tot += __shfl_xor(tot, 2);
    tot += __shfl_xor(tot, 4);
    tot += __shfl_xor(tot, 8);
    if (lane == 0)
        atomicAdd(out + seq, tot * 0.6931471805599453f);
}

extern "C" void kernel_launch(void* const* d_in, const int* in_sizes, int n_in,
                              void* d_out, int out_size, void* d_ws, size_t ws_size,
                              hipStream_t stream) {
    const float* x  = (const float*)d_in[0];   // [B,T,M] one-hot
    const float* I  = (const float*)d_in[1];   // [1,S]
    const float* A  = (const float*)d_in[2];   // [S,S]
    const float* Bm = (const float*)d_in[3];   // [M,S]
    float* out = (float*)d_out;                // [B,1]
    (void)d_ws; (void)ws_size;                 // workspace unused (fully fused)

    hipMemsetAsync(out, 0, (size_t)out_size * sizeof(float), stream);
    hmm_fused<<<(BATCH * 4) / WPB, WPB * 64, 0, stream>>>(x, I, A, Bm, out);  // 2048 waves
}